// Round 1
// 476.093 us; speedup vs baseline: 1.0029x; 1.0029x over previous
//
#include <hip/hip_runtime.h>
#include <cstring>

// Scene splat, gather formulation v5.
// R1: 41M global atomics cap at 65 Gops/s -> gather inversion (994->519 us).
// R2/R4: ~308 us of dur_us is harness poison/restore (fixed floor); gather
//        ~165 us vs ~90 us traffic floor. dwordx4 fast path helped (-33).
// R5: channel-merge (5x MLP) was NEUTRAL -> not latency-bound on reads.
// R6 A/B: nt stores -> PLAIN stores (win). Writes terminate in L2/L3.
// R7 (this): XCD-contiguous tile swizzle. Theory: default round-robin puts
//   horizontally-adjacent tiles on different XCDs, so (a) the 128B cache line
//   straddling each patch's x-split is fetched from HBM by BOTH tiles
//   (~80 MB duplicate reads, ~50% read amp) and (b) adjacent 256B write
//   segments drain interleaved from 8 L2s instead of merging into sequential
//   HBM runs. Swizzle tile = (bid&7)*512 + bid>>3 gives each XCD 8 contiguous
//   tile-rows: boundary lines L2-hit, writes aggregate. Single-variable change
//   vs R6. Predict: gather FETCH -15..25%, total 477 -> ~440-455 us.

typedef float vf4 __attribute__((ext_vector_type(4)));

constexpr int C  = 5;
constexpr int H  = 4096;
constexpr int W  = 4096;
constexpr int N  = 2000;
constexpr int PH = 64;
constexpr int PW = 64;

constexpr int TILE   = 64;
constexpr int TX     = W / TILE;        // 64
constexpr int TY     = H / TILE;        // 64
constexpr int NTILES = TX * TY;         // 4096
constexpr int CAP    = 128;             // mean ~2 entries/tile; tail << 128

__global__ __launch_bounds__(256) void bin_patches(
    const int2* __restrict__ positions,
    int*        __restrict__ counts,    // [NTILES]
    int2*       __restrict__ lists)     // [NTILES][CAP] : {n, (py<<16)|px}
{
    int n = blockIdx.x * blockDim.x + threadIdx.x;
    if (n >= N) return;
    int2 p = positions[n];              // .x = row offset, .y = col offset
    int packed = (p.x << 16) | p.y;     // both < 4096, fit 16b
    int ty0 = p.x >> 6, ty1 = (p.x + PH - 1) >> 6;
    int tx0 = p.y >> 6, tx1 = (p.y + PW - 1) >> 6;
    for (int ty = ty0; ty <= ty1; ++ty)
        for (int tx = tx0; tx <= tx1; ++tx) {
            int tile = ty * TX + tx;
            int slot = atomicAdd(&counts[tile], 1);
            if (slot < CAP) lists[tile * CAP + slot] = make_int2(n, packed);
        }
}

__global__ __launch_bounds__(256) void gather_tiles(
    const float* __restrict__ patches,   // (N, C, PH, PW)
    const int*   __restrict__ counts,
    const int2*  __restrict__ lists,
    float*       __restrict__ out)       // (C, H, W)
{
    // R7: XCD-contiguous swizzle. Dispatch round-robins consecutive blockIdx
    // across the 8 XCDs; remap so XCD k owns tiles [512k, 512k+512) = 8
    // contiguous tile-rows. Bijective since NTILES % 8 == 0.
    int bid  = blockIdx.x;
    int tile = ((bid & 7) << 9) | (bid >> 3);

    int y0 = (tile >> 6) << 6;
    int x0 = (tile & (TX - 1)) << 6;
    int t  = threadIdx.x;
    int row4 = t >> 4;                   // 0..15; thread owns rows row4+16k
    int colb = (t & 15) << 2;            // first of 4 consecutive cols owned

    vf4 acc[C][4] = {};                  // 80 VGPRs of accumulator

    int cnt = counts[tile];
    if (cnt > CAP) cnt = CAP;
    const int2* lst = lists + (size_t)tile * CAP;

    for (int i = 0; i < cnt; ++i) {
        int2 e = lst[i];                 // e.x = n, e.y = (py<<16)|px
        int py = e.y >> 16;
        int px = e.y & 0xffff;
        const float* pb = patches + (size_t)e.x * (C * PH * PW);
        int ry  = y0 - py;               // patch row of tile row 0
        int rxb = x0 - px + colb;        // patch col of this thread's chunk

        bool xfull = (unsigned)rxb <= (unsigned)(PW - 4);
        #pragma unroll
        for (int k = 0; k < 4; ++k) {
            int pr = ry + row4 + 16 * k;
            if ((unsigned)pr >= (unsigned)PH) continue;
            const float* prow = pb + pr * PW;
            if (xfull) {
                #pragma unroll
                for (int c = 0; c < C; ++c) {     // 5 independent dwordx4s
                    vf4 v;
                    __builtin_memcpy(&v, prow + c * (PH * PW) + rxb, sizeof(vf4));
                    acc[c][k] += v;
                }
            } else {
                #pragma unroll
                for (int j = 0; j < 4; ++j) {
                    int pxx = rxb + j;
                    if ((unsigned)pxx < (unsigned)PW) {
                        #pragma unroll
                        for (int c = 0; c < C; ++c)
                            acc[c][k][j] += prow[c * (PH * PW) + pxx];
                    }
                }
            }
        }
    }

    // Final writeback: PLAIN stores (R6 win). Writes may terminate in L2/L3
    // and write back after kernel end; zero tiles write zeros (replaces the
    // full-frame memset).
    #pragma unroll
    for (int c = 0; c < C; ++c) {
        vf4* o4 = (vf4*)(out + ((size_t)c * H + y0) * W + x0);
        #pragma unroll
        for (int k = 0; k < 4; ++k) {
            int yy = row4 + 16 * k;
            o4[(size_t)yy * (W / 4) + (colb >> 2)] = acc[c][k];
        }
    }
}

extern "C" void kernel_launch(void* const* d_in, const int* in_sizes, int n_in,
                              void* d_out, int out_size, void* d_ws, size_t ws_size,
                              hipStream_t stream) {
    const float* patches   = (const float*)d_in[0];
    const int2*  positions = (const int2*)d_in[1];
    float*       out       = (float*)d_out;

    int*  counts = (int*)d_ws;                       // NTILES ints
    int2* lists  = (int2*)(counts + NTILES);         // NTILES*CAP int2 (4 MB)

    (void)hipMemsetAsync(counts, 0, NTILES * sizeof(int), stream);

    bin_patches<<<(N + 255) / 256, 256, 0, stream>>>(positions, counts, lists);

    gather_tiles<<<NTILES, 256, 0, stream>>>(patches, counts, lists, out);
}